// Round 3
// baseline (2703.808 us; speedup 1.0000x reference)
//
#include <hip/hip_runtime.h>

#define NN 100000
#define NE 3200000
#define FIN 128
#define FH 64
#define FO 64
#define NG 128
#define NB 3125   // buckets of 32 nodes: 3125*32 == 100000 exactly

// ---------------- init: zero bucket counters + output ----------------
__global__ void k_init(int* __restrict__ bcnt, int* __restrict__ bcur,
                       float* __restrict__ out) {
  int i = blockIdx.x * blockDim.x + threadIdx.x;
  if (i < NB) { bcnt[i] = 0; bcur[i] = 0; }
  if (i < NG * (FO + FH)) out[i] = 0.0f;
}

// ---------------- bucket histogram (LDS-privatized) ----------------
__global__ __launch_bounds__(256) void k_hist(const int* __restrict__ ei,
                                              int* __restrict__ bcnt) {
  __shared__ int lh[NB];
  int tid = threadIdx.x;
  for (int i = tid; i < NB; i += 256) lh[i] = 0;
  __syncthreads();
  const int EPB = NE / 128;  // 25000 edges per block
  int base = blockIdx.x * EPB;
  for (int i = tid; i < EPB; i += 256) {
    int d = ei[NE + base + i];
    atomicAdd(&lh[d >> 5], 1);
  }
  __syncthreads();
  for (int i = tid; i < NB; i += 256)
    if (lh[i]) atomicAdd(&bcnt[i], lh[i]);
}

// ---------------- exclusive scan of 3125 bucket counts ----------------
__global__ __launch_bounds__(1024) void k_bscan(const int* __restrict__ bcnt,
                                                int* __restrict__ boff) {
  __shared__ int part[1024];
  int tid = threadIdx.x;
  int start = tid * 4;
  int end = min(start + 4, NB);
  if (start > NB) start = NB;
  int s = 0;
  for (int i = start; i < end; ++i) s += bcnt[i];
  part[tid] = s;
  __syncthreads();
  for (int d = 1; d < 1024; d <<= 1) {
    int t = (tid >= d) ? part[tid - d] : 0;
    __syncthreads();
    part[tid] += t;
    __syncthreads();
  }
  int off = part[tid] - s;
  for (int i = start; i < end; ++i) { boff[i] = off; off += bcnt[i]; }
  if (tid == 1023) boff[NB] = part[1023];
}

// ---------------- scatter edges into buckets, packed (src<<5)|(dst&31) ----------------
__global__ void k_bscatter(const int* __restrict__ ei, const int* __restrict__ boff,
                           int* __restrict__ bcur, int* __restrict__ bucketed) {
  int e = blockIdx.x * blockDim.x + threadIdx.x;
  if (e < NE) {
    int s = ei[e];
    int d = ei[NE + e];
    int b = d >> 5;
    int pos = atomicAdd(&bcur[b], 1);
    bucketed[boff[b] + pos] = (s << 5) | (d & 31);
  }
}

// ---------------- per-node degree -> dinv, from bucketed edges ----------------
__global__ __launch_bounds__(64) void k_deg(const int* __restrict__ bucketed,
                                            const int* __restrict__ boff,
                                            float* __restrict__ dinv) {
  __shared__ int c[32];
  int b = blockIdx.x, t = threadIdx.x;
  if (t < 32) c[t] = 0;
  __syncthreads();
  int beg = boff[b], end = boff[b + 1];
  for (int i = beg + t; i < end; i += 64) atomicAdd(&c[bucketed[i] & 31], 1);
  __syncthreads();
  if (t < 32) dinv[b * 32 + t] = rsqrtf((float)c[t] + 1.0f);
}

// ---------------- root indices + graph node counts via binary search ----------------
__global__ __launch_bounds__(128) void k_root(const int* __restrict__ batch,
                                              int* __restrict__ root_idx,
                                              int* __restrict__ gcnt) {
  int g = threadIdx.x;
  if (g >= NG) return;
  int lo = 0, hi = NN;
  while (lo < hi) { int m = (lo + hi) >> 1; if (batch[m] < g) lo = m + 1; else hi = m; }
  int a = lo;
  lo = a; hi = NN;
  while (lo < hi) { int m = (lo + hi) >> 1; if (batch[m] < g + 1) lo = m + 1; else hi = m; }
  int b = lo;
  gcnt[g] = b - a;
  root_idx[g] = (b > a) ? a : (NN - 1);
}

// ---------------- GEMM1: ps1 = (x @ W1) * dinv[n]  [N,128]@[128,64] ----------------
__global__ __launch_bounds__(256) void k_gemm1(const float* __restrict__ x,
                                               const float* __restrict__ W1,
                                               const float* __restrict__ dinv,
                                               float* __restrict__ h) {
  __shared__ float Ws[FIN * FH];   // 32 KB
  __shared__ float Xs[16 * FIN];   // 8 KB
  int tid = threadIdx.x;
  for (int i = tid; i < FIN * FH; i += 256) Ws[i] = W1[i];
  long n0 = (long)blockIdx.x * 16;
  const float4* xg = (const float4*)(x + n0 * FIN);
  float4* xs4 = (float4*)Xs;
  for (int i = tid; i < 16 * FIN / 4; i += 256) xs4[i] = xg[i];
  __syncthreads();
  int f = tid & 63;
  int nl = tid >> 6;
  int b = nl * 4;
  float acc0 = 0.f, acc1 = 0.f, acc2 = 0.f, acc3 = 0.f;
  #pragma unroll 4
  for (int i = 0; i < FIN; i += 4) {
    float4 x0 = *(const float4*)&Xs[(b + 0) * FIN + i];
    float4 x1 = *(const float4*)&Xs[(b + 1) * FIN + i];
    float4 x2 = *(const float4*)&Xs[(b + 2) * FIN + i];
    float4 x3 = *(const float4*)&Xs[(b + 3) * FIN + i];
    float w0 = Ws[(i + 0) * FH + f];
    float w1 = Ws[(i + 1) * FH + f];
    float w2 = Ws[(i + 2) * FH + f];
    float w3 = Ws[(i + 3) * FH + f];
    acc0 += x0.x * w0 + x0.y * w1 + x0.z * w2 + x0.w * w3;
    acc1 += x1.x * w0 + x1.y * w1 + x1.z * w2 + x1.w * w3;
    acc2 += x2.x * w0 + x2.y * w1 + x2.z * w2 + x2.w * w3;
    acc3 += x3.x * w0 + x3.y * w1 + x3.z * w2 + x3.w * w3;
  }
  h[(n0 + b + 0) * FH + f] = acc0 * dinv[n0 + b + 0];
  h[(n0 + b + 1) * FH + f] = acc1 * dinv[n0 + b + 1];
  h[(n0 + b + 2) * FH + f] = acc2 * dinv[n0 + b + 2];
  h[(n0 + b + 3) * FH + f] = acc3 * dinv[n0 + b + 3];
}

// ---------------- per-graph root projection: relu(x[root]) @ W2[64:192,:] ----------------
__global__ __launch_bounds__(64) void k_rootproj(const float* __restrict__ x,
                                                 const float* __restrict__ W2,
                                                 const int* __restrict__ root_idx,
                                                 float* __restrict__ rp) {
  __shared__ float xr[FIN];
  int g = blockIdx.x;
  int t = threadIdx.x;
  long r = root_idx[g];
  xr[t]      = fmaxf(x[r * FIN + t], 0.0f);
  xr[t + 64] = fmaxf(x[r * FIN + t + 64], 0.0f);
  __syncthreads();
  float acc = 0.0f;
  #pragma unroll 8
  for (int i = 0; i < FIN; ++i) acc += xr[i] * W2[(FH + i) * FO + t];
  rp[g * FO + t] = acc;
}

// ---------------- bucketed aggregation ----------------
// out[n] = dinv[n]*(sum_{src->n} ps[src] + ps[n]) + bias;  ps already scaled by dinv[src]
template <int RELU>
__global__ __launch_bounds__(256) void k_agg(const float* __restrict__ ps,
                                             const float* __restrict__ dinv,
                                             const int* __restrict__ boff,
                                             const int* __restrict__ bucketed,
                                             const float* __restrict__ bias,
                                             float* __restrict__ outb) {
  __shared__ float acc[32 * FH];  // 8 KB
  int tid = threadIdx.x;
  int b = blockIdx.x;
  long base = (long)b * 32;
  // init with self term (coalesced)
  float4* a4 = (float4*)acc;
  const float4* p4 = (const float4*)(ps + base * FH);
  for (int i = tid; i < 32 * FH / 4; i += 256) a4[i] = p4[i];
  __syncthreads();
  int beg = boff[b], end = boff[b + 1];
  int lane = tid & 63, wv = tid >> 6;
  int m = end - beg;
  int chunk = (m + 3) >> 2;
  int ws = beg + wv * chunk;
  int we = min(ws + chunk, end);
  for (int s = ws; s < we; s += 64) {
    int w = (s + lane < we) ? bucketed[s + lane] : 0;
    int cnt = min(64, we - s);
    for (int j = 0; j < cnt; ++j) {
      int wj = __shfl(w, j);
      int sn = wj >> 5;
      int d5 = wj & 31;
      float v = ps[(long)sn * FH + lane];
      atomicAdd(&acc[d5 * FH + lane], v);
    }
  }
  __syncthreads();
  for (int i = tid; i < 32 * FH; i += 256) {
    long n = base + (i >> 6);
    float val = dinv[n] * acc[i] + bias[i & 63];
    if (RELU) val = fmaxf(val, 0.0f);
    outb[n * FH + (i & 63)] = val;
  }
}

// ---------------- GEMM2: ps2 = (relu(h1) @ W2[0:64,:] + rp[batch]) * dinv ----------------
__global__ __launch_bounds__(256) void k_gemm2(const float* __restrict__ h1,
                                               const float* __restrict__ W2,
                                               const float* __restrict__ rp,
                                               const int* __restrict__ batch,
                                               const float* __restrict__ dinv,
                                               float* __restrict__ h2) {
  __shared__ float Ws[FH * FO];   // 16 KB
  __shared__ float Hs[16 * FH];   // 4 KB
  int tid = threadIdx.x;
  for (int i = tid; i < FH * FO; i += 256) Ws[i] = W2[i];
  long n0 = (long)blockIdx.x * 16;
  for (int i = tid; i < 16 * FH; i += 256) Hs[i] = fmaxf(h1[n0 * FH + i], 0.0f);
  __syncthreads();
  int f = tid & 63;
  int nl = tid >> 6;
  int b = nl * 4;
  float acc0 = rp[(long)batch[n0 + b + 0] * FO + f];
  float acc1 = rp[(long)batch[n0 + b + 1] * FO + f];
  float acc2 = rp[(long)batch[n0 + b + 2] * FO + f];
  float acc3 = rp[(long)batch[n0 + b + 3] * FO + f];
  #pragma unroll 4
  for (int j = 0; j < FH; j += 4) {
    float4 h0 = *(const float4*)&Hs[(b + 0) * FH + j];
    float4 h1v = *(const float4*)&Hs[(b + 1) * FH + j];
    float4 h2v = *(const float4*)&Hs[(b + 2) * FH + j];
    float4 h3 = *(const float4*)&Hs[(b + 3) * FH + j];
    float w0 = Ws[(j + 0) * FO + f];
    float w1 = Ws[(j + 1) * FO + f];
    float w2 = Ws[(j + 2) * FO + f];
    float w3 = Ws[(j + 3) * FO + f];
    acc0 += h0.x * w0 + h0.y * w1 + h0.z * w2 + h0.w * w3;
    acc1 += h1v.x * w0 + h1v.y * w1 + h1v.z * w2 + h1v.w * w3;
    acc2 += h2v.x * w0 + h2v.y * w1 + h2v.z * w2 + h2v.w * w3;
    acc3 += h3.x * w0 + h3.y * w1 + h3.z * w2 + h3.w * w3;
  }
  h2[(n0 + b + 0) * FH + f] = acc0 * dinv[n0 + b + 0];
  h2[(n0 + b + 1) * FH + f] = acc1 * dinv[n0 + b + 1];
  h2[(n0 + b + 2) * FH + f] = acc2 * dinv[n0 + b + 2];
  h2[(n0 + b + 3) * FH + f] = acc3 * dinv[n0 + b + 3];
}

// ---------------- mean-pool: segment sums of r over batch ----------------
__global__ __launch_bounds__(64) void k_pool(const float* __restrict__ r,
                                             const int* __restrict__ batch,
                                             float* __restrict__ out) {
  const int PC = 100;
  int lane = threadIdx.x;
  long n0 = (long)blockIdx.x * PC;
  long n1 = n0 + PC;
  if (n1 > NN) n1 = NN;
  if (n0 >= NN) return;
  float acc = 0.0f;
  int cur = batch[n0];
  for (long n = n0; n < n1; ++n) {
    int g = batch[n];
    if (g != cur) {
      atomicAdd(&out[(long)cur * (FO + FH) + lane], acc);
      acc = 0.0f;
      cur = g;
    }
    acc += r[n * FH + lane];
  }
  atomicAdd(&out[(long)cur * (FO + FH) + lane], acc);
}

// ---------------- finalize: divide by count; fill root2 half ----------------
__global__ void k_final(float* __restrict__ out, const int* __restrict__ gcnt,
                        const int* __restrict__ root_idx, const float* __restrict__ h1full) {
  int i = blockIdx.x * blockDim.x + threadIdx.x;
  if (i >= NG * FO) return;
  int g = i >> 6, f = i & 63;
  int c = gcnt[g];
  float inv = 1.0f / fmaxf((float)c, 1.0f);
  out[g * (FO + FH) + f] *= inv;
  out[g * (FO + FH) + FO + f] = (c > 0) ? h1full[(long)root_idx[g] * FH + f] : 0.0f;
}

extern "C" void kernel_launch(void* const* d_in, const int* in_sizes, int n_in,
                              void* d_out, int out_size, void* d_ws, size_t ws_size,
                              hipStream_t stream) {
  const float* x   = (const float*)d_in[0];
  const int*   ei  = (const int*)d_in[1];
  const int*   bat = (const int*)d_in[2];
  const float* W1  = (const float*)d_in[3];
  const float* b1  = (const float*)d_in[4];
  const float* W2  = (const float*)d_in[5];
  const float* b2  = (const float*)d_in[6];
  float* out = (float*)d_out;

  char* p = (char*)d_ws;
  auto carve = [&](size_t bytes) -> void* {
    char* q = p;
    p += (bytes + 511) & ~size_t(511);
    return (void*)q;
  };
  float* dinv     = (float*)carve((size_t)NN * 4);
  int*   bcnt     = (int*)carve((size_t)NB * 4);
  int*   boff     = (int*)carve((size_t)(NB + 1) * 4);
  int*   bcur     = (int*)carve((size_t)NB * 4);
  int*   bucketed = (int*)carve((size_t)NE * 4);
  float* bufA     = (float*)carve((size_t)NN * FH * 4);  // ps1, later r
  float* bufB     = (float*)carve((size_t)NN * FH * 4);  // h1
  float* bufC     = (float*)carve((size_t)NN * FH * 4);  // ps2
  int*   root_i   = (int*)carve((size_t)NG * 4);
  int*   gcnt     = (int*)carve((size_t)NG * 4);
  float* rp       = (float*)carve((size_t)NG * FO * 4);

  k_init<<<64, 256, 0, stream>>>(bcnt, bcur, out);
  k_hist<<<128, 256, 0, stream>>>(ei, bcnt);
  k_bscan<<<1, 1024, 0, stream>>>(bcnt, boff);
  k_bscatter<<<(NE + 255) / 256, 256, 0, stream>>>(ei, boff, bcur, bucketed);
  k_deg<<<NB, 64, 0, stream>>>(bucketed, boff, dinv);
  k_gemm1<<<NN / 16, 256, 0, stream>>>(x, W1, dinv, bufA);
  k_root<<<1, 128, 0, stream>>>(bat, root_i, gcnt);
  k_rootproj<<<NG, 64, 0, stream>>>(x, W2, root_i, rp);
  k_agg<0><<<NB, 256, 0, stream>>>(bufA, dinv, boff, bucketed, b1, bufB);
  k_gemm2<<<NN / 16, 256, 0, stream>>>(bufB, W2, rp, bat, dinv, bufC);
  k_agg<1><<<NB, 256, 0, stream>>>(bufC, dinv, boff, bucketed, b2, bufA);
  k_pool<<<(NN + 99) / 100, 64, 0, stream>>>(bufA, bat, out);
  k_final<<<(NG * FO + 255) / 256, 256, 0, stream>>>(out, gcnt, root_i, bufB);
}

// Round 4
// 695.368 us; speedup vs baseline: 3.8883x; 3.8883x over previous
//
#include <hip/hip_runtime.h>

#define NN 100000
#define NE 3200000
#define FIN 128
#define FH 64
#define FO 64
#define NG 128
#define NB 3125   // buckets of 32 nodes: 3125*32 == 100000 exactly

// ---------------- init: zero bucket counters + output ----------------
__global__ void k_init(int* __restrict__ bcnt, int* __restrict__ bcur,
                       float* __restrict__ out) {
  int i = blockIdx.x * blockDim.x + threadIdx.x;
  if (i < NB) { bcnt[i] = 0; bcur[i] = 0; }
  if (i < NG * (FO + FH)) out[i] = 0.0f;
}

// ---------------- bucket histogram (LDS-privatized) ----------------
__global__ __launch_bounds__(256) void k_hist(const int* __restrict__ ei,
                                              int* __restrict__ bcnt) {
  __shared__ int lh[NB];
  int tid = threadIdx.x;
  for (int i = tid; i < NB; i += 256) lh[i] = 0;
  __syncthreads();
  const int EPB = NE / 128;  // 25000 edges per block
  int base = blockIdx.x * EPB;
  for (int i = tid; i < EPB; i += 256) {
    int d = ei[NE + base + i];
    atomicAdd(&lh[d >> 5], 1);
  }
  __syncthreads();
  for (int i = tid; i < NB; i += 256)
    if (lh[i]) atomicAdd(&bcnt[i], lh[i]);
}

// ---------------- exclusive scan of 3125 bucket counts ----------------
__global__ __launch_bounds__(1024) void k_bscan(const int* __restrict__ bcnt,
                                                int* __restrict__ boff) {
  __shared__ int part[1024];
  int tid = threadIdx.x;
  int start = tid * 4;
  int end = min(start + 4, NB);
  if (start > NB) start = NB;
  int s = 0;
  for (int i = start; i < end; ++i) s += bcnt[i];
  part[tid] = s;
  __syncthreads();
  for (int d = 1; d < 1024; d <<= 1) {
    int t = (tid >= d) ? part[tid - d] : 0;
    __syncthreads();
    part[tid] += t;
    __syncthreads();
  }
  int off = part[tid] - s;
  for (int i = start; i < end; ++i) { boff[i] = off; off += bcnt[i]; }
  if (tid == 1023) boff[NB] = part[1023];
}

// ---------------- scatter edges into buckets, packed (src<<5)|(dst&31) ----------------
__global__ void k_bscatter(const int* __restrict__ ei, const int* __restrict__ boff,
                           int* __restrict__ bcur, int* __restrict__ bucketed) {
  int e = blockIdx.x * blockDim.x + threadIdx.x;
  if (e < NE) {
    int s = ei[e];
    int d = ei[NE + e];
    int b = d >> 5;
    int pos = atomicAdd(&bcur[b], 1);
    bucketed[boff[b] + pos] = (s << 5) | (d & 31);
  }
}

// ---------------- within-bucket counting sort -> per-node CSR + dinv ----------------
__global__ __launch_bounds__(256) void k_perm(const int* __restrict__ bucketed,
                                              const int* __restrict__ boff,
                                              int* __restrict__ rowptr,
                                              float* __restrict__ dinv,
                                              int* __restrict__ csr_src) {
  __shared__ int c[32], pref[32], cur[32];
  int b = blockIdx.x, tid = threadIdx.x;
  if (tid < 32) { c[tid] = 0; cur[tid] = 0; }
  __syncthreads();
  int beg = boff[b], end = boff[b + 1];
  for (int i = beg + tid; i < end; i += 256) atomicAdd(&c[bucketed[i] & 31], 1);
  __syncthreads();
  if (tid == 0) {
    int run = 0;
    for (int j = 0; j < 32; ++j) { pref[j] = run; run += c[j]; }
  }
  __syncthreads();
  if (tid < 32) {
    rowptr[b * 32 + tid] = beg + pref[tid];
    dinv[b * 32 + tid] = rsqrtf((float)c[tid] + 1.0f);
  }
  if (b == 0 && tid == 32) rowptr[NN] = NE;
  __syncthreads();
  for (int i = beg + tid; i < end; i += 256) {
    int w = bucketed[i];
    int d = w & 31;
    int pos = atomicAdd(&cur[d], 1);
    csr_src[beg + pref[d] + pos] = w >> 5;
  }
}

// ---------------- root indices + graph node counts via binary search ----------------
__global__ __launch_bounds__(128) void k_root(const int* __restrict__ batch,
                                              int* __restrict__ root_idx,
                                              int* __restrict__ gcnt) {
  int g = threadIdx.x;
  if (g >= NG) return;
  int lo = 0, hi = NN;
  while (lo < hi) { int m = (lo + hi) >> 1; if (batch[m] < g) lo = m + 1; else hi = m; }
  int a = lo;
  lo = a; hi = NN;
  while (lo < hi) { int m = (lo + hi) >> 1; if (batch[m] < g + 1) lo = m + 1; else hi = m; }
  int b = lo;
  gcnt[g] = b - a;
  root_idx[g] = (b > a) ? a : (NN - 1);
}

// ---------------- GEMM1: ps1 = (x @ W1) * dinv[n]  [N,128]@[128,64] ----------------
__global__ __launch_bounds__(256) void k_gemm1(const float* __restrict__ x,
                                               const float* __restrict__ W1,
                                               const float* __restrict__ dinv,
                                               float* __restrict__ h) {
  __shared__ float Ws[FIN * FH];   // 32 KB
  __shared__ float Xs[16 * FIN];   // 8 KB
  int tid = threadIdx.x;
  for (int i = tid; i < FIN * FH; i += 256) Ws[i] = W1[i];
  long n0 = (long)blockIdx.x * 16;
  const float4* xg = (const float4*)(x + n0 * FIN);
  float4* xs4 = (float4*)Xs;
  for (int i = tid; i < 16 * FIN / 4; i += 256) xs4[i] = xg[i];
  __syncthreads();
  int f = tid & 63;
  int nl = tid >> 6;
  int b = nl * 4;
  float acc0 = 0.f, acc1 = 0.f, acc2 = 0.f, acc3 = 0.f;
  #pragma unroll 4
  for (int i = 0; i < FIN; i += 4) {
    float4 x0 = *(const float4*)&Xs[(b + 0) * FIN + i];
    float4 x1 = *(const float4*)&Xs[(b + 1) * FIN + i];
    float4 x2 = *(const float4*)&Xs[(b + 2) * FIN + i];
    float4 x3 = *(const float4*)&Xs[(b + 3) * FIN + i];
    float w0 = Ws[(i + 0) * FH + f];
    float w1 = Ws[(i + 1) * FH + f];
    float w2 = Ws[(i + 2) * FH + f];
    float w3 = Ws[(i + 3) * FH + f];
    acc0 += x0.x * w0 + x0.y * w1 + x0.z * w2 + x0.w * w3;
    acc1 += x1.x * w0 + x1.y * w1 + x1.z * w2 + x1.w * w3;
    acc2 += x2.x * w0 + x2.y * w1 + x2.z * w2 + x2.w * w3;
    acc3 += x3.x * w0 + x3.y * w1 + x3.z * w2 + x3.w * w3;
  }
  h[(n0 + b + 0) * FH + f] = acc0 * dinv[n0 + b + 0];
  h[(n0 + b + 1) * FH + f] = acc1 * dinv[n0 + b + 1];
  h[(n0 + b + 2) * FH + f] = acc2 * dinv[n0 + b + 2];
  h[(n0 + b + 3) * FH + f] = acc3 * dinv[n0 + b + 3];
}

// ---------------- per-graph root projection: relu(x[root]) @ W2[64:192,:] ----------------
__global__ __launch_bounds__(64) void k_rootproj(const float* __restrict__ x,
                                                 const float* __restrict__ W2,
                                                 const int* __restrict__ root_idx,
                                                 float* __restrict__ rp) {
  __shared__ float xr[FIN];
  int g = blockIdx.x;
  int t = threadIdx.x;
  long r = root_idx[g];
  xr[t]      = fmaxf(x[r * FIN + t], 0.0f);
  xr[t + 64] = fmaxf(x[r * FIN + t + 64], 0.0f);
  __syncthreads();
  float acc = 0.0f;
  #pragma unroll 8
  for (int i = 0; i < FIN; ++i) acc += xr[i] * W2[(FH + i) * FO + t];
  rp[g * FO + t] = acc;
}

// ---------------- per-node aggregation (wave per node, register acc) ----------------
// ps is pre-scaled by dinv[src]; out[n] = dinv[n]*(ps[n] + sum ps[src]) + bias
template <int RELU>
__global__ __launch_bounds__(256) void k_agg(const float* __restrict__ ps,
                                             const float* __restrict__ dinv,
                                             const int* __restrict__ rowptr,
                                             const int* __restrict__ csr_src,
                                             const float* __restrict__ bias,
                                             float* __restrict__ outb) {
  int wave = threadIdx.x >> 6;
  int lane = threadIdx.x & 63;
  int n = blockIdx.x * 4 + wave;
  if (n >= NN) return;
  float acc = ps[(long)n * FH + lane];  // self term (prescaled)
  int beg = rowptr[n], end = rowptr[n + 1];
  int i = beg;
  for (; i + 4 <= end; i += 4) {
    int s0 = csr_src[i + 0];
    int s1 = csr_src[i + 1];
    int s2 = csr_src[i + 2];
    int s3 = csr_src[i + 3];
    float v0 = ps[(long)s0 * FH + lane];
    float v1 = ps[(long)s1 * FH + lane];
    float v2 = ps[(long)s2 * FH + lane];
    float v3 = ps[(long)s3 * FH + lane];
    acc += v0;
    acc += v1;
    acc += v2;
    acc += v3;
  }
  for (; i < end; ++i) acc += ps[(long)csr_src[i] * FH + lane];
  float val = dinv[n] * acc + bias[lane];
  if (RELU) val = fmaxf(val, 0.0f);
  outb[(long)n * FH + lane] = val;
}

// ---------------- GEMM2: ps2 = (relu(h1) @ W2[0:64,:] + rp[batch]) * dinv ----------------
__global__ __launch_bounds__(256) void k_gemm2(const float* __restrict__ h1,
                                               const float* __restrict__ W2,
                                               const float* __restrict__ rp,
                                               const int* __restrict__ batch,
                                               const float* __restrict__ dinv,
                                               float* __restrict__ h2) {
  __shared__ float Ws[FH * FO];   // 16 KB
  __shared__ float Hs[16 * FH];   // 4 KB
  int tid = threadIdx.x;
  for (int i = tid; i < FH * FO; i += 256) Ws[i] = W2[i];
  long n0 = (long)blockIdx.x * 16;
  for (int i = tid; i < 16 * FH; i += 256) Hs[i] = fmaxf(h1[n0 * FH + i], 0.0f);
  __syncthreads();
  int f = tid & 63;
  int nl = tid >> 6;
  int b = nl * 4;
  float acc0 = rp[(long)batch[n0 + b + 0] * FO + f];
  float acc1 = rp[(long)batch[n0 + b + 1] * FO + f];
  float acc2 = rp[(long)batch[n0 + b + 2] * FO + f];
  float acc3 = rp[(long)batch[n0 + b + 3] * FO + f];
  #pragma unroll 4
  for (int j = 0; j < FH; j += 4) {
    float4 h0 = *(const float4*)&Hs[(b + 0) * FH + j];
    float4 h1v = *(const float4*)&Hs[(b + 1) * FH + j];
    float4 h2v = *(const float4*)&Hs[(b + 2) * FH + j];
    float4 h3 = *(const float4*)&Hs[(b + 3) * FH + j];
    float w0 = Ws[(j + 0) * FO + f];
    float w1 = Ws[(j + 1) * FO + f];
    float w2 = Ws[(j + 2) * FO + f];
    float w3 = Ws[(j + 3) * FO + f];
    acc0 += h0.x * w0 + h0.y * w1 + h0.z * w2 + h0.w * w3;
    acc1 += h1v.x * w0 + h1v.y * w1 + h1v.z * w2 + h1v.w * w3;
    acc2 += h2v.x * w0 + h2v.y * w1 + h2v.z * w2 + h2v.w * w3;
    acc3 += h3.x * w0 + h3.y * w1 + h3.z * w2 + h3.w * w3;
  }
  h2[(n0 + b + 0) * FH + f] = acc0 * dinv[n0 + b + 0];
  h2[(n0 + b + 1) * FH + f] = acc1 * dinv[n0 + b + 1];
  h2[(n0 + b + 2) * FH + f] = acc2 * dinv[n0 + b + 2];
  h2[(n0 + b + 3) * FH + f] = acc3 * dinv[n0 + b + 3];
}

// ---------------- mean-pool: segment sums of r over batch ----------------
__global__ __launch_bounds__(64) void k_pool(const float* __restrict__ r,
                                             const int* __restrict__ batch,
                                             float* __restrict__ out) {
  const int PC = 100;
  int lane = threadIdx.x;
  long n0 = (long)blockIdx.x * PC;
  long n1 = n0 + PC;
  if (n1 > NN) n1 = NN;
  if (n0 >= NN) return;
  float acc = 0.0f;
  int cur = batch[n0];
  for (long n = n0; n < n1; ++n) {
    int g = batch[n];
    if (g != cur) {
      atomicAdd(&out[(long)cur * (FO + FH) + lane], acc);
      acc = 0.0f;
      cur = g;
    }
    acc += r[n * FH + lane];
  }
  atomicAdd(&out[(long)cur * (FO + FH) + lane], acc);
}

// ---------------- finalize: divide by count; fill root2 half ----------------
__global__ void k_final(float* __restrict__ out, const int* __restrict__ gcnt,
                        const int* __restrict__ root_idx, const float* __restrict__ h1full) {
  int i = blockIdx.x * blockDim.x + threadIdx.x;
  if (i >= NG * FO) return;
  int g = i >> 6, f = i & 63;
  int c = gcnt[g];
  float inv = 1.0f / fmaxf((float)c, 1.0f);
  out[g * (FO + FH) + f] *= inv;
  out[g * (FO + FH) + FO + f] = (c > 0) ? h1full[(long)root_idx[g] * FH + f] : 0.0f;
}

extern "C" void kernel_launch(void* const* d_in, const int* in_sizes, int n_in,
                              void* d_out, int out_size, void* d_ws, size_t ws_size,
                              hipStream_t stream) {
  const float* x   = (const float*)d_in[0];
  const int*   ei  = (const int*)d_in[1];
  const int*   bat = (const int*)d_in[2];
  const float* W1  = (const float*)d_in[3];
  const float* b1  = (const float*)d_in[4];
  const float* W2  = (const float*)d_in[5];
  const float* b2  = (const float*)d_in[6];
  float* out = (float*)d_out;

  char* p = (char*)d_ws;
  auto carve = [&](size_t bytes) -> void* {
    char* q = p;
    p += (bytes + 511) & ~size_t(511);
    return (void*)q;
  };
  float* dinv     = (float*)carve((size_t)NN * 4);
  int*   bcnt     = (int*)carve((size_t)NB * 4);
  int*   boff     = (int*)carve((size_t)(NB + 1) * 4);
  int*   bcur     = (int*)carve((size_t)NB * 4);
  int*   bucketed = (int*)carve((size_t)NE * 4);
  int*   rowptr   = (int*)carve((size_t)(NN + 1) * 4);
  int*   csr_src  = (int*)carve((size_t)NE * 4);
  float* bufA     = (float*)carve((size_t)NN * FH * 4);  // ps1, later r
  float* bufB     = (float*)carve((size_t)NN * FH * 4);  // h1
  float* bufC     = (float*)carve((size_t)NN * FH * 4);  // ps2
  int*   root_i   = (int*)carve((size_t)NG * 4);
  int*   gcnt     = (int*)carve((size_t)NG * 4);
  float* rp       = (float*)carve((size_t)NG * FO * 4);

  k_init<<<64, 256, 0, stream>>>(bcnt, bcur, out);
  k_hist<<<128, 256, 0, stream>>>(ei, bcnt);
  k_bscan<<<1, 1024, 0, stream>>>(bcnt, boff);
  k_bscatter<<<(NE + 255) / 256, 256, 0, stream>>>(ei, boff, bcur, bucketed);
  k_perm<<<NB, 256, 0, stream>>>(bucketed, boff, rowptr, dinv, csr_src);
  k_gemm1<<<NN / 16, 256, 0, stream>>>(x, W1, dinv, bufA);
  k_root<<<1, 128, 0, stream>>>(bat, root_i, gcnt);
  k_rootproj<<<NG, 64, 0, stream>>>(x, W2, root_i, rp);
  k_agg<0><<<(NN + 3) / 4, 256, 0, stream>>>(bufA, dinv, rowptr, csr_src, b1, bufB);
  k_gemm2<<<NN / 16, 256, 0, stream>>>(bufB, W2, rp, bat, dinv, bufC);
  k_agg<1><<<(NN + 3) / 4, 256, 0, stream>>>(bufC, dinv, rowptr, csr_src, b2, bufA);
  k_pool<<<(NN + 99) / 100, 64, 0, stream>>>(bufA, bat, out);
  k_final<<<(NG * FO + 255) / 256, 256, 0, stream>>>(out, gcnt, root_i, bufB);
}

// Round 5
// 481.788 us; speedup vs baseline: 5.6120x; 1.4433x over previous
//
#include <hip/hip_runtime.h>

#define NN 100000
#define NE 3200000
#define FIN 128
#define FH 64
#define FO 64
#define NG 128
#define NB 3125   // buckets of 32 nodes: 3125*32 == 100000 exactly

// ---------------- init: zero bucket counters + output ----------------
__global__ void k_init(int* __restrict__ bcnt, int* __restrict__ bcur,
                       float* __restrict__ out) {
  int i = blockIdx.x * blockDim.x + threadIdx.x;
  if (i < NB) { bcnt[i] = 0; bcur[i] = 0; }
  if (i < NG * (FO + FH)) out[i] = 0.0f;
}

// ---------------- bucket histogram (LDS-privatized) ----------------
__global__ __launch_bounds__(256) void k_hist(const int* __restrict__ ei,
                                              int* __restrict__ bcnt) {
  __shared__ int lh[NB];
  int tid = threadIdx.x;
  for (int i = tid; i < NB; i += 256) lh[i] = 0;
  __syncthreads();
  const int EPB = NE / 128;  // 25000 edges per block
  int base = blockIdx.x * EPB;
  for (int i = tid; i < EPB; i += 256) {
    int d = ei[NE + base + i];
    atomicAdd(&lh[d >> 5], 1);
  }
  __syncthreads();
  for (int i = tid; i < NB; i += 256)
    if (lh[i]) atomicAdd(&bcnt[i], lh[i]);
}

// ---------------- exclusive scan of 3125 bucket counts ----------------
__global__ __launch_bounds__(1024) void k_bscan(const int* __restrict__ bcnt,
                                                int* __restrict__ boff) {
  __shared__ int part[1024];
  int tid = threadIdx.x;
  int start = tid * 4;
  int end = min(start + 4, NB);
  if (start > NB) start = NB;
  int s = 0;
  for (int i = start; i < end; ++i) s += bcnt[i];
  part[tid] = s;
  __syncthreads();
  for (int d = 1; d < 1024; d <<= 1) {
    int t = (tid >= d) ? part[tid - d] : 0;
    __syncthreads();
    part[tid] += t;
    __syncthreads();
  }
  int off = part[tid] - s;
  for (int i = start; i < end; ++i) { boff[i] = off; off += bcnt[i]; }
  if (tid == 1023) boff[NB] = part[1023];
}

// ---------------- two-phase block-local scatter into buckets ----------------
// Each block reserves contiguous per-bucket runs -> coalesced-ish writes,
// ~400K global atomics instead of 3.2M, line ownership ~2 XCDs instead of 8.
__global__ __launch_bounds__(256) void k_bscatter(const int* __restrict__ ei,
                                                  const int* __restrict__ boff,
                                                  int* __restrict__ bcur,
                                                  int* __restrict__ bucketed) {
  __shared__ int lbase[NB];  // count, then global base for this block
  __shared__ int lcur[NB];   // within-block cursor
  const int EPB = NE / 128;  // 25000
  int base = blockIdx.x * EPB;
  int tid = threadIdx.x;
  for (int i = tid; i < NB; i += 256) { lbase[i] = 0; lcur[i] = 0; }
  __syncthreads();
  for (int i = tid; i < EPB; i += 256) {
    int d = ei[NE + base + i];
    atomicAdd(&lbase[d >> 5], 1);
  }
  __syncthreads();
  for (int i = tid; i < NB; i += 256) {
    int c = lbase[i];
    lbase[i] = c ? (boff[i] + atomicAdd(&bcur[i], c)) : 0;
  }
  __syncthreads();
  for (int i = tid; i < EPB; i += 256) {
    int s = ei[base + i];
    int d = ei[NE + base + i];
    int b = d >> 5;
    int pos = atomicAdd(&lcur[b], 1);
    bucketed[lbase[b] + pos] = (s << 5) | (d & 31);
  }
}

// ---------------- within-bucket counting sort -> per-node CSR + dinv ----------------
__global__ __launch_bounds__(256) void k_perm(const int* __restrict__ bucketed,
                                              const int* __restrict__ boff,
                                              int* __restrict__ rowptr,
                                              float* __restrict__ dinv,
                                              int* __restrict__ csr_src) {
  __shared__ int c[32], pref[32], cur[32];
  int b = blockIdx.x, tid = threadIdx.x;
  if (tid < 32) { c[tid] = 0; cur[tid] = 0; }
  __syncthreads();
  int beg = boff[b], end = boff[b + 1];
  for (int i = beg + tid; i < end; i += 256) atomicAdd(&c[bucketed[i] & 31], 1);
  __syncthreads();
  if (tid == 0) {
    int run = 0;
    for (int j = 0; j < 32; ++j) { pref[j] = run; run += c[j]; }
  }
  __syncthreads();
  if (tid < 32) {
    rowptr[b * 32 + tid] = beg + pref[tid];
    dinv[b * 32 + tid] = rsqrtf((float)c[tid] + 1.0f);
  }
  if (b == 0 && tid == 32) rowptr[NN] = NE;
  __syncthreads();
  for (int i = beg + tid; i < end; i += 256) {
    int w = bucketed[i];
    int d = w & 31;
    int pos = atomicAdd(&cur[d], 1);
    csr_src[beg + pref[d] + pos] = w >> 5;
  }
}

// ---------------- root indices + graph node counts via binary search ----------------
__global__ __launch_bounds__(128) void k_root(const int* __restrict__ batch,
                                              int* __restrict__ root_idx,
                                              int* __restrict__ gcnt) {
  int g = threadIdx.x;
  if (g >= NG) return;
  int lo = 0, hi = NN;
  while (lo < hi) { int m = (lo + hi) >> 1; if (batch[m] < g) lo = m + 1; else hi = m; }
  int a = lo;
  lo = a; hi = NN;
  while (lo < hi) { int m = (lo + hi) >> 1; if (batch[m] < g + 1) lo = m + 1; else hi = m; }
  int b = lo;
  gcnt[g] = b - a;
  root_idx[g] = (b > a) ? a : (NN - 1);
}

// ---------------- GEMM1: ps1 = (x @ W1) * dinv[n]  [N,128]@[128,64] ----------------
__global__ __launch_bounds__(256) void k_gemm1(const float* __restrict__ x,
                                               const float* __restrict__ W1,
                                               const float* __restrict__ dinv,
                                               float* __restrict__ h) {
  __shared__ float Ws[FIN * FH];   // 32 KB
  __shared__ float Xs[16 * FIN];   // 8 KB
  int tid = threadIdx.x;
  for (int i = tid; i < FIN * FH; i += 256) Ws[i] = W1[i];
  long n0 = (long)blockIdx.x * 16;
  const float4* xg = (const float4*)(x + n0 * FIN);
  float4* xs4 = (float4*)Xs;
  for (int i = tid; i < 16 * FIN / 4; i += 256) xs4[i] = xg[i];
  __syncthreads();
  int f = tid & 63;
  int nl = tid >> 6;
  int b = nl * 4;
  float acc0 = 0.f, acc1 = 0.f, acc2 = 0.f, acc3 = 0.f;
  #pragma unroll 4
  for (int i = 0; i < FIN; i += 4) {
    float4 x0 = *(const float4*)&Xs[(b + 0) * FIN + i];
    float4 x1 = *(const float4*)&Xs[(b + 1) * FIN + i];
    float4 x2 = *(const float4*)&Xs[(b + 2) * FIN + i];
    float4 x3 = *(const float4*)&Xs[(b + 3) * FIN + i];
    float w0 = Ws[(i + 0) * FH + f];
    float w1 = Ws[(i + 1) * FH + f];
    float w2 = Ws[(i + 2) * FH + f];
    float w3 = Ws[(i + 3) * FH + f];
    acc0 += x0.x * w0 + x0.y * w1 + x0.z * w2 + x0.w * w3;
    acc1 += x1.x * w0 + x1.y * w1 + x1.z * w2 + x1.w * w3;
    acc2 += x2.x * w0 + x2.y * w1 + x2.z * w2 + x2.w * w3;
    acc3 += x3.x * w0 + x3.y * w1 + x3.z * w2 + x3.w * w3;
  }
  h[(n0 + b + 0) * FH + f] = acc0 * dinv[n0 + b + 0];
  h[(n0 + b + 1) * FH + f] = acc1 * dinv[n0 + b + 1];
  h[(n0 + b + 2) * FH + f] = acc2 * dinv[n0 + b + 2];
  h[(n0 + b + 3) * FH + f] = acc3 * dinv[n0 + b + 3];
}

// ---------------- per-graph root projection: relu(x[root]) @ W2[64:192,:] ----------------
__global__ __launch_bounds__(64) void k_rootproj(const float* __restrict__ x,
                                                 const float* __restrict__ W2,
                                                 const int* __restrict__ root_idx,
                                                 float* __restrict__ rp) {
  __shared__ float xr[FIN];
  int g = blockIdx.x;
  int t = threadIdx.x;
  long r = root_idx[g];
  xr[t]      = fmaxf(x[r * FIN + t], 0.0f);
  xr[t + 64] = fmaxf(x[r * FIN + t + 64], 0.0f);
  __syncthreads();
  float acc = 0.0f;
  #pragma unroll 8
  for (int i = 0; i < FIN; ++i) acc += xr[i] * W2[(FH + i) * FO + t];
  rp[g * FO + t] = acc;
}

// ---------------- per-node aggregation (wave per node, register acc) ----------------
template <int RELU>
__global__ __launch_bounds__(256) void k_agg(const float* __restrict__ ps,
                                             const float* __restrict__ dinv,
                                             const int* __restrict__ rowptr,
                                             const int* __restrict__ csr_src,
                                             const float* __restrict__ bias,
                                             float* __restrict__ outb) {
  int wave = threadIdx.x >> 6;
  int lane = threadIdx.x & 63;
  int n = blockIdx.x * 4 + wave;
  if (n >= NN) return;
  float acc = ps[(long)n * FH + lane];  // self term (prescaled)
  int beg = rowptr[n], end = rowptr[n + 1];
  int i = beg;
  for (; i + 4 <= end; i += 4) {
    int s0 = csr_src[i + 0];
    int s1 = csr_src[i + 1];
    int s2 = csr_src[i + 2];
    int s3 = csr_src[i + 3];
    float v0 = ps[(long)s0 * FH + lane];
    float v1 = ps[(long)s1 * FH + lane];
    float v2 = ps[(long)s2 * FH + lane];
    float v3 = ps[(long)s3 * FH + lane];
    acc += v0;
    acc += v1;
    acc += v2;
    acc += v3;
  }
  for (; i < end; ++i) acc += ps[(long)csr_src[i] * FH + lane];
  float val = dinv[n] * acc + bias[lane];
  if (RELU) val = fmaxf(val, 0.0f);
  outb[(long)n * FH + lane] = val;
}

// ---------------- GEMM2: ps2 = (relu(h1) @ W2[0:64,:] + rp[batch]) * dinv ----------------
__global__ __launch_bounds__(256) void k_gemm2(const float* __restrict__ h1,
                                               const float* __restrict__ W2,
                                               const float* __restrict__ rp,
                                               const int* __restrict__ batch,
                                               const float* __restrict__ dinv,
                                               float* __restrict__ h2) {
  __shared__ float Ws[FH * FO];   // 16 KB
  __shared__ float Hs[16 * FH];   // 4 KB
  int tid = threadIdx.x;
  for (int i = tid; i < FH * FO; i += 256) Ws[i] = W2[i];
  long n0 = (long)blockIdx.x * 16;
  for (int i = tid; i < 16 * FH; i += 256) Hs[i] = fmaxf(h1[n0 * FH + i], 0.0f);
  __syncthreads();
  int f = tid & 63;
  int nl = tid >> 6;
  int b = nl * 4;
  float acc0 = rp[(long)batch[n0 + b + 0] * FO + f];
  float acc1 = rp[(long)batch[n0 + b + 1] * FO + f];
  float acc2 = rp[(long)batch[n0 + b + 2] * FO + f];
  float acc3 = rp[(long)batch[n0 + b + 3] * FO + f];
  #pragma unroll 4
  for (int j = 0; j < FH; j += 4) {
    float4 h0 = *(const float4*)&Hs[(b + 0) * FH + j];
    float4 h1v = *(const float4*)&Hs[(b + 1) * FH + j];
    float4 h2v = *(const float4*)&Hs[(b + 2) * FH + j];
    float4 h3 = *(const float4*)&Hs[(b + 3) * FH + j];
    float w0 = Ws[(j + 0) * FO + f];
    float w1 = Ws[(j + 1) * FO + f];
    float w2 = Ws[(j + 2) * FO + f];
    float w3 = Ws[(j + 3) * FO + f];
    acc0 += h0.x * w0 + h0.y * w1 + h0.z * w2 + h0.w * w3;
    acc1 += h1v.x * w0 + h1v.y * w1 + h1v.z * w2 + h1v.w * w3;
    acc2 += h2v.x * w0 + h2v.y * w1 + h2v.z * w2 + h2v.w * w3;
    acc3 += h3.x * w0 + h3.y * w1 + h3.z * w2 + h3.w * w3;
  }
  h2[(n0 + b + 0) * FH + f] = acc0 * dinv[n0 + b + 0];
  h2[(n0 + b + 1) * FH + f] = acc1 * dinv[n0 + b + 1];
  h2[(n0 + b + 2) * FH + f] = acc2 * dinv[n0 + b + 2];
  h2[(n0 + b + 3) * FH + f] = acc3 * dinv[n0 + b + 3];
}

// ---------------- mean-pool: segment sums of r over batch ----------------
__global__ __launch_bounds__(64) void k_pool(const float* __restrict__ r,
                                             const int* __restrict__ batch,
                                             float* __restrict__ out) {
  const int PC = 100;
  int lane = threadIdx.x;
  long n0 = (long)blockIdx.x * PC;
  long n1 = n0 + PC;
  if (n1 > NN) n1 = NN;
  if (n0 >= NN) return;
  float acc = 0.0f;
  int cur = batch[n0];
  for (long n = n0; n < n1; ++n) {
    int g = batch[n];
    if (g != cur) {
      atomicAdd(&out[(long)cur * (FO + FH) + lane], acc);
      acc = 0.0f;
      cur = g;
    }
    acc += r[n * FH + lane];
  }
  atomicAdd(&out[(long)cur * (FO + FH) + lane], acc);
}

// ---------------- finalize: divide by count; fill root2 half ----------------
__global__ void k_final(float* __restrict__ out, const int* __restrict__ gcnt,
                        const int* __restrict__ root_idx, const float* __restrict__ h1full) {
  int i = blockIdx.x * blockDim.x + threadIdx.x;
  if (i >= NG * FO) return;
  int g = i >> 6, f = i & 63;
  int c = gcnt[g];
  float inv = 1.0f / fmaxf((float)c, 1.0f);
  out[g * (FO + FH) + f] *= inv;
  out[g * (FO + FH) + FO + f] = (c > 0) ? h1full[(long)root_idx[g] * FH + f] : 0.0f;
}

extern "C" void kernel_launch(void* const* d_in, const int* in_sizes, int n_in,
                              void* d_out, int out_size, void* d_ws, size_t ws_size,
                              hipStream_t stream) {
  const float* x   = (const float*)d_in[0];
  const int*   ei  = (const int*)d_in[1];
  const int*   bat = (const int*)d_in[2];
  const float* W1  = (const float*)d_in[3];
  const float* b1  = (const float*)d_in[4];
  const float* W2  = (const float*)d_in[5];
  const float* b2  = (const float*)d_in[6];
  float* out = (float*)d_out;

  char* p = (char*)d_ws;
  auto carve = [&](size_t bytes) -> void* {
    char* q = p;
    p += (bytes + 511) & ~size_t(511);
    return (void*)q;
  };
  float* dinv     = (float*)carve((size_t)NN * 4);
  int*   bcnt     = (int*)carve((size_t)NB * 4);
  int*   boff     = (int*)carve((size_t)(NB + 1) * 4);
  int*   bcur     = (int*)carve((size_t)NB * 4);
  int*   bucketed = (int*)carve((size_t)NE * 4);
  int*   rowptr   = (int*)carve((size_t)(NN + 1) * 4);
  int*   csr_src  = (int*)carve((size_t)NE * 4);
  float* bufA     = (float*)carve((size_t)NN * FH * 4);  // ps1, later r
  float* bufB     = (float*)carve((size_t)NN * FH * 4);  // h1
  float* bufC     = (float*)carve((size_t)NN * FH * 4);  // ps2
  int*   root_i   = (int*)carve((size_t)NG * 4);
  int*   gcnt     = (int*)carve((size_t)NG * 4);
  float* rp       = (float*)carve((size_t)NG * FO * 4);

  k_init<<<64, 256, 0, stream>>>(bcnt, bcur, out);
  k_hist<<<128, 256, 0, stream>>>(ei, bcnt);
  k_bscan<<<1, 1024, 0, stream>>>(bcnt, boff);
  k_bscatter<<<128, 256, 0, stream>>>(ei, boff, bcur, bucketed);
  k_perm<<<NB, 256, 0, stream>>>(bucketed, boff, rowptr, dinv, csr_src);
  k_gemm1<<<NN / 16, 256, 0, stream>>>(x, W1, dinv, bufA);
  k_root<<<1, 128, 0, stream>>>(bat, root_i, gcnt);
  k_rootproj<<<NG, 64, 0, stream>>>(x, W2, root_i, rp);
  k_agg<0><<<(NN + 3) / 4, 256, 0, stream>>>(bufA, dinv, rowptr, csr_src, b1, bufB);
  k_gemm2<<<NN / 16, 256, 0, stream>>>(bufB, W2, rp, bat, dinv, bufC);
  k_agg<1><<<(NN + 3) / 4, 256, 0, stream>>>(bufC, dinv, rowptr, csr_src, b2, bufA);
  k_pool<<<(NN + 99) / 100, 64, 0, stream>>>(bufA, bat, out);
  k_final<<<(NG * FO + 255) / 256, 256, 0, stream>>>(out, gcnt, root_i, bufB);
}

// Round 6
// 424.348 us; speedup vs baseline: 6.3717x; 1.1354x over previous
//
#include <hip/hip_runtime.h>
#include <hip/hip_bf16.h>

#define NN 100000
#define NE 3200000
#define FIN 128
#define FH 64
#define FO 64
#define NG 128
#define NP 98        // partitions of 1024 nodes (98*1024 = 100352 >= NN)
#define PSH 10       // partition shift
#define ECAP 36000   // max edges per partition (expect 32768 +/- 181)

// ---------------- init: zero partition counters + output ----------------
__global__ void k_init(int* __restrict__ pcnt, int* __restrict__ pcur,
                       float* __restrict__ out) {
  int i = blockIdx.x * blockDim.x + threadIdx.x;
  if (i < NP) { pcnt[i] = 0; pcur[i] = 0; }
  if (i < NG * (FO + FH)) out[i] = 0.0f;
}

// ---------------- partition histogram ----------------
__global__ __launch_bounds__(256) void k_phist(const int* __restrict__ ei,
                                               int* __restrict__ pcnt) {
  __shared__ int lh[NP];
  int tid = threadIdx.x;
  if (tid < NP) lh[tid] = 0;
  __syncthreads();
  const int EPB = NE / 256;  // 12500
  int base = blockIdx.x * EPB;
  for (int i = tid; i < EPB; i += 256) atomicAdd(&lh[ei[NE + base + i] >> PSH], 1);
  __syncthreads();
  if (tid < NP && lh[tid]) atomicAdd(&pcnt[tid], lh[tid]);
}

// ---------------- tiny serial scan of 98 partition counts ----------------
__global__ void k_pscan(const int* __restrict__ pcnt, int* __restrict__ poff) {
  if (threadIdx.x == 0) {
    int run = 0;
    for (int i = 0; i < NP; ++i) { poff[i] = run; run += pcnt[i]; }
    poff[NP] = run;  // == NE
  }
}

// ---------------- two-phase block-local scatter into partitions ----------------
// runs of ~128 edges (512B) per block*partition -> write amp ~1
__global__ __launch_bounds__(256) void k_pscatter(const int* __restrict__ ei,
                                                  const int* __restrict__ poff,
                                                  int* __restrict__ pcur,
                                                  int* __restrict__ part_e) {
  __shared__ int lbase[NP];
  __shared__ int lcur[NP];
  const int EPB = NE / 256;  // 12500
  int base = blockIdx.x * EPB;
  int tid = threadIdx.x;
  if (tid < NP) { lbase[tid] = 0; lcur[tid] = 0; }
  __syncthreads();
  for (int i = tid; i < EPB; i += 256) atomicAdd(&lbase[ei[NE + base + i] >> PSH], 1);
  __syncthreads();
  if (tid < NP) {
    int c = lbase[tid];
    lbase[tid] = c ? (poff[tid] + atomicAdd(&pcur[tid], c)) : 0;
  }
  __syncthreads();
  for (int i = tid; i < EPB; i += 256) {
    int s = ei[base + i];
    int d = ei[NE + base + i];
    int p = d >> PSH;
    int pos = atomicAdd(&lcur[p], 1);
    part_e[lbase[p] + pos] = (s << PSH) | (d & 1023);  // s < 2^17 -> fits 27 bits
  }
}

// ---------------- per-partition LDS counting sort -> CSR + rowptr + dinv ----------------
__global__ __launch_bounds__(1024) void k_psort(const int* __restrict__ part_e,
                                                const int* __restrict__ poff,
                                                int* __restrict__ rowptr,
                                                float* __restrict__ dinv,
                                                int* __restrict__ csr_src) {
  __shared__ int ew[ECAP];     // 144 KB
  __shared__ int cnt[1024];    // 4 KB
  __shared__ int pref[1024];   // 4 KB
  int p = blockIdx.x, tid = threadIdx.x;
  int beg = poff[p], end = poff[p + 1];
  int m = end - beg;
  for (int i = tid; i < m; i += 1024) ew[i] = part_e[beg + i];
  cnt[tid] = 0;
  __syncthreads();
  for (int i = tid; i < m; i += 1024) atomicAdd(&cnt[ew[i] & 1023], 1);
  __syncthreads();
  pref[tid] = cnt[tid];
  __syncthreads();
  for (int d = 1; d < 1024; d <<= 1) {
    int t = (tid >= d) ? pref[tid - d] : 0;
    __syncthreads();
    pref[tid] += t;
    __syncthreads();
  }
  int excl = pref[tid] - cnt[tid];
  int n = p * 1024 + tid;
  if (n < NN) {
    rowptr[n] = beg + excl;
    dinv[n] = rsqrtf((float)cnt[tid] + 1.0f);
  }
  if (p == 0 && tid == 0) rowptr[NN] = NE;
  __syncthreads();
  pref[tid] = excl;  // becomes the scatter cursor
  __syncthreads();
  for (int i = tid; i < m; i += 1024) {
    int w = ew[i];
    int pos = atomicAdd(&pref[w & 1023], 1);
    csr_src[beg + pos] = w >> PSH;
  }
}

// ---------------- root indices + graph node counts via binary search ----------------
__global__ __launch_bounds__(128) void k_root(const int* __restrict__ batch,
                                              int* __restrict__ root_idx,
                                              int* __restrict__ gcnt) {
  int g = threadIdx.x;
  if (g >= NG) return;
  int lo = 0, hi = NN;
  while (lo < hi) { int m = (lo + hi) >> 1; if (batch[m] < g) lo = m + 1; else hi = m; }
  int a = lo;
  lo = a; hi = NN;
  while (lo < hi) { int m = (lo + hi) >> 1; if (batch[m] < g + 1) lo = m + 1; else hi = m; }
  int b = lo;
  gcnt[g] = b - a;
  root_idx[g] = (b > a) ? a : (NN - 1);
}

// ---------------- GEMM1: ps1 = bf16((x @ W1) * dinv[n]) ----------------
__global__ __launch_bounds__(256) void k_gemm1(const float* __restrict__ x,
                                               const float* __restrict__ W1,
                                               const float* __restrict__ dinv,
                                               __hip_bfloat16* __restrict__ ps) {
  __shared__ float Ws[FIN * FH];   // 32 KB
  __shared__ float Xs[16 * FIN];   // 8 KB
  int tid = threadIdx.x;
  for (int i = tid; i < FIN * FH; i += 256) Ws[i] = W1[i];
  long n0 = (long)blockIdx.x * 16;
  const float4* xg = (const float4*)(x + n0 * FIN);
  float4* xs4 = (float4*)Xs;
  for (int i = tid; i < 16 * FIN / 4; i += 256) xs4[i] = xg[i];
  __syncthreads();
  int f = tid & 63;
  int nl = tid >> 6;
  int b = nl * 4;
  float acc0 = 0.f, acc1 = 0.f, acc2 = 0.f, acc3 = 0.f;
  #pragma unroll 4
  for (int i = 0; i < FIN; i += 4) {
    float4 x0 = *(const float4*)&Xs[(b + 0) * FIN + i];
    float4 x1 = *(const float4*)&Xs[(b + 1) * FIN + i];
    float4 x2 = *(const float4*)&Xs[(b + 2) * FIN + i];
    float4 x3 = *(const float4*)&Xs[(b + 3) * FIN + i];
    float w0 = Ws[(i + 0) * FH + f];
    float w1 = Ws[(i + 1) * FH + f];
    float w2 = Ws[(i + 2) * FH + f];
    float w3 = Ws[(i + 3) * FH + f];
    acc0 += x0.x * w0 + x0.y * w1 + x0.z * w2 + x0.w * w3;
    acc1 += x1.x * w0 + x1.y * w1 + x1.z * w2 + x1.w * w3;
    acc2 += x2.x * w0 + x2.y * w1 + x2.z * w2 + x2.w * w3;
    acc3 += x3.x * w0 + x3.y * w1 + x3.z * w2 + x3.w * w3;
  }
  ps[(n0 + b + 0) * FH + f] = __float2bfloat16(acc0 * dinv[n0 + b + 0]);
  ps[(n0 + b + 1) * FH + f] = __float2bfloat16(acc1 * dinv[n0 + b + 1]);
  ps[(n0 + b + 2) * FH + f] = __float2bfloat16(acc2 * dinv[n0 + b + 2]);
  ps[(n0 + b + 3) * FH + f] = __float2bfloat16(acc3 * dinv[n0 + b + 3]);
}

// ---------------- per-graph root projection: relu(x[root]) @ W2[64:192,:] ----------------
__global__ __launch_bounds__(64) void k_rootproj(const float* __restrict__ x,
                                                 const float* __restrict__ W2,
                                                 const int* __restrict__ root_idx,
                                                 float* __restrict__ rp) {
  __shared__ float xr[FIN];
  int g = blockIdx.x;
  int t = threadIdx.x;
  long r = root_idx[g];
  xr[t]      = fmaxf(x[r * FIN + t], 0.0f);
  xr[t + 64] = fmaxf(x[r * FIN + t + 64], 0.0f);
  __syncthreads();
  float acc = 0.0f;
  #pragma unroll 8
  for (int i = 0; i < FIN; ++i) acc += xr[i] * W2[(FH + i) * FO + t];
  rp[g * FO + t] = acc;
}

// ---------------- per-node aggregation (wave per node, bf16 gather, fp32 acc) ----------------
template <int RELU>
__global__ __launch_bounds__(256) void k_agg(const __hip_bfloat16* __restrict__ ps,
                                             const float* __restrict__ dinv,
                                             const int* __restrict__ rowptr,
                                             const int* __restrict__ csr_src,
                                             const float* __restrict__ bias,
                                             float* __restrict__ outb) {
  int wave = threadIdx.x >> 6;
  int lane = threadIdx.x & 63;
  int n = blockIdx.x * 4 + wave;
  if (n >= NN) return;
  float acc = __bfloat162float(ps[(long)n * FH + lane]);  // self term (prescaled)
  int beg = rowptr[n], end = rowptr[n + 1];
  int i = beg;
  for (; i + 4 <= end; i += 4) {
    int s0 = csr_src[i + 0];
    int s1 = csr_src[i + 1];
    int s2 = csr_src[i + 2];
    int s3 = csr_src[i + 3];
    float v0 = __bfloat162float(ps[(long)s0 * FH + lane]);
    float v1 = __bfloat162float(ps[(long)s1 * FH + lane]);
    float v2 = __bfloat162float(ps[(long)s2 * FH + lane]);
    float v3 = __bfloat162float(ps[(long)s3 * FH + lane]);
    acc += v0;
    acc += v1;
    acc += v2;
    acc += v3;
  }
  for (; i < end; ++i) acc += __bfloat162float(ps[(long)csr_src[i] * FH + lane]);
  float val = dinv[n] * acc + bias[lane];
  if (RELU) val = fmaxf(val, 0.0f);
  outb[(long)n * FH + lane] = val;
}

// ---------------- GEMM2: ps2 = bf16((relu(h1) @ W2[0:64,:] + rp[batch]) * dinv) ----------------
__global__ __launch_bounds__(256) void k_gemm2(const float* __restrict__ h1,
                                               const float* __restrict__ W2,
                                               const float* __restrict__ rp,
                                               const int* __restrict__ batch,
                                               const float* __restrict__ dinv,
                                               __hip_bfloat16* __restrict__ ps2) {
  __shared__ float Ws[FH * FO];   // 16 KB
  __shared__ float Hs[16 * FH];   // 4 KB
  int tid = threadIdx.x;
  for (int i = tid; i < FH * FO; i += 256) Ws[i] = W2[i];
  long n0 = (long)blockIdx.x * 16;
  for (int i = tid; i < 16 * FH; i += 256) Hs[i] = fmaxf(h1[n0 * FH + i], 0.0f);
  __syncthreads();
  int f = tid & 63;
  int nl = tid >> 6;
  int b = nl * 4;
  float acc0 = rp[(long)batch[n0 + b + 0] * FO + f];
  float acc1 = rp[(long)batch[n0 + b + 1] * FO + f];
  float acc2 = rp[(long)batch[n0 + b + 2] * FO + f];
  float acc3 = rp[(long)batch[n0 + b + 3] * FO + f];
  #pragma unroll 4
  for (int j = 0; j < FH; j += 4) {
    float4 h0 = *(const float4*)&Hs[(b + 0) * FH + j];
    float4 h1v = *(const float4*)&Hs[(b + 1) * FH + j];
    float4 h2v = *(const float4*)&Hs[(b + 2) * FH + j];
    float4 h3 = *(const float4*)&Hs[(b + 3) * FH + j];
    float w0 = Ws[(j + 0) * FO + f];
    float w1 = Ws[(j + 1) * FO + f];
    float w2 = Ws[(j + 2) * FO + f];
    float w3 = Ws[(j + 3) * FO + f];
    acc0 += h0.x * w0 + h0.y * w1 + h0.z * w2 + h0.w * w3;
    acc1 += h1v.x * w0 + h1v.y * w1 + h1v.z * w2 + h1v.w * w3;
    acc2 += h2v.x * w0 + h2v.y * w1 + h2v.z * w2 + h2v.w * w3;
    acc3 += h3.x * w0 + h3.y * w1 + h3.z * w2 + h3.w * w3;
  }
  ps2[(n0 + b + 0) * FH + f] = __float2bfloat16(acc0 * dinv[n0 + b + 0]);
  ps2[(n0 + b + 1) * FH + f] = __float2bfloat16(acc1 * dinv[n0 + b + 1]);
  ps2[(n0 + b + 2) * FH + f] = __float2bfloat16(acc2 * dinv[n0 + b + 2]);
  ps2[(n0 + b + 3) * FH + f] = __float2bfloat16(acc3 * dinv[n0 + b + 3]);
}

// ---------------- mean-pool: segment sums of r over batch ----------------
__global__ __launch_bounds__(64) void k_pool(const float* __restrict__ r,
                                             const int* __restrict__ batch,
                                             float* __restrict__ out) {
  const int PC = 100;
  int lane = threadIdx.x;
  long n0 = (long)blockIdx.x * PC;
  long n1 = n0 + PC;
  if (n1 > NN) n1 = NN;
  if (n0 >= NN) return;
  float acc = 0.0f;
  int cur = batch[n0];
  for (long n = n0; n < n1; ++n) {
    int g = batch[n];
    if (g != cur) {
      atomicAdd(&out[(long)cur * (FO + FH) + lane], acc);
      acc = 0.0f;
      cur = g;
    }
    acc += r[n * FH + lane];
  }
  atomicAdd(&out[(long)cur * (FO + FH) + lane], acc);
}

// ---------------- finalize: divide by count; fill root2 half ----------------
__global__ void k_final(float* __restrict__ out, const int* __restrict__ gcnt,
                        const int* __restrict__ root_idx, const float* __restrict__ h1full) {
  int i = blockIdx.x * blockDim.x + threadIdx.x;
  if (i >= NG * FO) return;
  int g = i >> 6, f = i & 63;
  int c = gcnt[g];
  float inv = 1.0f / fmaxf((float)c, 1.0f);
  out[g * (FO + FH) + f] *= inv;
  out[g * (FO + FH) + FO + f] = (c > 0) ? h1full[(long)root_idx[g] * FH + f] : 0.0f;
}

extern "C" void kernel_launch(void* const* d_in, const int* in_sizes, int n_in,
                              void* d_out, int out_size, void* d_ws, size_t ws_size,
                              hipStream_t stream) {
  const float* x   = (const float*)d_in[0];
  const int*   ei  = (const int*)d_in[1];
  const int*   bat = (const int*)d_in[2];
  const float* W1  = (const float*)d_in[3];
  const float* b1  = (const float*)d_in[4];
  const float* W2  = (const float*)d_in[5];
  const float* b2  = (const float*)d_in[6];
  float* out = (float*)d_out;

  char* p = (char*)d_ws;
  auto carve = [&](size_t bytes) -> void* {
    char* q = p;
    p += (bytes + 511) & ~size_t(511);
    return (void*)q;
  };
  float* dinv    = (float*)carve((size_t)NN * 4);
  int*   pcnt    = (int*)carve((size_t)NP * 4);
  int*   poff    = (int*)carve((size_t)(NP + 1) * 4);
  int*   pcur    = (int*)carve((size_t)NP * 4);
  int*   part_e  = (int*)carve((size_t)NE * 4);
  int*   rowptr  = (int*)carve((size_t)(NN + 1) * 4);
  int*   csr_src = (int*)carve((size_t)NE * 4);
  __hip_bfloat16* psA = (__hip_bfloat16*)carve((size_t)NN * FH * 2);  // ps1 bf16
  __hip_bfloat16* psB = (__hip_bfloat16*)carve((size_t)NN * FH * 2);  // ps2 bf16
  float* bufB    = (float*)carve((size_t)NN * FH * 4);  // h1 fp32
  float* bufD    = (float*)carve((size_t)NN * FH * 4);  // r  fp32
  int*   root_i  = (int*)carve((size_t)NG * 4);
  int*   gcnt    = (int*)carve((size_t)NG * 4);
  float* rp      = (float*)carve((size_t)NG * FO * 4);

  k_init<<<64, 256, 0, stream>>>(pcnt, pcur, out);
  k_phist<<<256, 256, 0, stream>>>(ei, pcnt);
  k_pscan<<<1, 64, 0, stream>>>(pcnt, poff);
  k_pscatter<<<256, 256, 0, stream>>>(ei, poff, pcur, part_e);
  k_psort<<<NP, 1024, 0, stream>>>(part_e, poff, rowptr, dinv, csr_src);
  k_gemm1<<<NN / 16, 256, 0, stream>>>(x, W1, dinv, psA);
  k_root<<<1, 128, 0, stream>>>(bat, root_i, gcnt);
  k_rootproj<<<NG, 64, 0, stream>>>(x, W2, root_i, rp);
  k_agg<0><<<(NN + 3) / 4, 256, 0, stream>>>(psA, dinv, rowptr, csr_src, b1, bufB);
  k_gemm2<<<NN / 16, 256, 0, stream>>>(bufB, W2, rp, bat, dinv, psB);
  k_agg<1><<<(NN + 3) / 4, 256, 0, stream>>>(psB, dinv, rowptr, csr_src, b2, bufD);
  k_pool<<<(NN + 99) / 100, 64, 0, stream>>>(bufD, bat, out);
  k_final<<<(NG * FO + 255) / 256, 256, 0, stream>>>(out, gcnt, root_i, bufB);
}